// Round 8
// baseline (8340.099 us; speedup 1.0000x reference)
//
#include <hip/hip_runtime.h>

#define BB 256
#define LL 128
#define HH 512
#define H4 2048

typedef unsigned short us;
typedef unsigned long long u64;
typedef __attribute__((ext_vector_type(8))) __bf16 bf16x8;
typedef __attribute__((ext_vector_type(4))) float f32x4;

__device__ __forceinline__ float bf2f(us s) {
    unsigned u = ((unsigned)s) << 16;
    return __builtin_bit_cast(float, u);
}
__device__ __forceinline__ us f2bf(float f) {
    unsigned u = __builtin_bit_cast(unsigned, f);
    return (us)((u + 0x7fffu + ((u >> 16) & 1u)) >> 16);
}
__device__ __forceinline__ float sigm(float x) { return 1.f / (1.f + __expf(-x)); }
__device__ __forceinline__ float tanh_(float x) { return 1.f - 2.f / (1.f + __expf(2.f * x)); }
__device__ __forceinline__ bf16x8 ldb8(const us* p) { return *(const bf16x8*)(const void*)p; }

// ---- device-coherent (L2-bypassing, sc1) accessors for cross-block recurrent data ----
__device__ __forceinline__ bf16x8 ldb8_dev(const us* p) {
    union { u64 q[2]; bf16x8 v; } u;
    u.q[0] = __hip_atomic_load((const u64*)(const void*)p, __ATOMIC_RELAXED, __HIP_MEMORY_SCOPE_AGENT);
    u.q[1] = __hip_atomic_load((const u64*)(const void*)p + 1, __ATOMIC_RELAXED, __HIP_MEMORY_SCOPE_AGENT);
    return u.v;
}
// lanes (2i,2i+1) hold adjacent bf16 columns of the same row: even lane stores packed 4B
__device__ __forceinline__ void st_pair_dev(us* p, unsigned myv, int lane) {
    unsigned ov = __shfl_xor(myv, 1);
    if (!(lane & 1)) {
        unsigned pk = (myv & 0xffffu) | (ov << 16);
        __hip_atomic_store((unsigned*)(void*)p, pk, __ATOMIC_RELAXED, __HIP_MEMORY_SCOPE_AGENT);
    }
}

// ---- fence-free group barrier (r5-proven): flag per block on its OWN 64B line,
// 16 pollers each polling a distinct line -> polls pipeline, no hot-line serialization ----
__device__ __forceinline__ void gsync_nf(unsigned* flags, int myidx, int base, unsigned target) {
    __syncthreads();  // all waves arrived; per-wave vmcnt drained -> sc1 stores visible
    if (threadIdx.x < 64) {
        if (threadIdx.x == 0)
            __hip_atomic_store(flags + (size_t)myidx * 16, target, __ATOMIC_RELAXED,
                               __HIP_MEMORY_SCOPE_AGENT);
        for (int i = (int)threadIdx.x; i < 16; i += 64)
            while (__hip_atomic_load(flags + (size_t)(base + i) * 16, __ATOMIC_RELAXED,
                                     __HIP_MEMORY_SCOPE_AGENT) < target) {}
        asm volatile("" ::: "memory");
    }
    __syncthreads();
}

// ---- fenced full-grid barrier (L2 wb + inv) — used exactly TWICE ----
__device__ __forceinline__ void gsync_f(unsigned* flags, int myidx, unsigned target) {
    __syncthreads();
    if (threadIdx.x < 64) {
        if (threadIdx.x == 0) {
            __builtin_amdgcn_fence(__ATOMIC_RELEASE, "agent");
            __hip_atomic_store(flags + (size_t)myidx * 16, target, __ATOMIC_RELAXED,
                               __HIP_MEMORY_SCOPE_AGENT);
        }
        for (int i = (int)threadIdx.x; i < 256; i += 64)
            while (__hip_atomic_load(flags + (size_t)i * 16, __ATOMIC_RELAXED,
                                     __HIP_MEMORY_SCOPE_AGENT) < target) {}
        __builtin_amdgcn_fence(__ATOMIC_ACQUIRE, "agent");
    }
    __syncthreads();
}

// A-fragment read from a 16x512 bf16 staged tile in LDS (XOR swizzle vs bank conflicts).
__device__ __forceinline__ bf16x8 ldfragA(const char* buf, int l15, int quad, int kk) {
    int off = ((kk << 6) + (quad << 4)) ^ ((l15 & 7) << 4);
    return *(const bf16x8*)(buf + (l15 << 10) + off);
}

// Persistent cooperative kernel. Group = 16 blocks (blockIdx & 15).
// Residences: decoder weights + enc_w1[own batch] in REGISTERS; enc_out context reads
// from L2 (resident); recurrent h/q/ctx/din via sc1; spread-line fence-free barriers.
extern "C" __global__ void __launch_bounds__(512) k_mega(
    const int* __restrict__ xs, const int* __restrict__ argsort,
    const float* __restrict__ enc_Wi, const float* __restrict__ enc_Wh, const float* __restrict__ enc_b,
    const float* __restrict__ dec_Wi, const float* __restrict__ dec_Wh, const float* __restrict__ dec_b,
    const float* __restrict__ w1, const float* __restrict__ w2, const float* __restrict__ vt,
    float* __restrict__ out, char* __restrict__ ws) {
    unsigned* flags = (unsigned*)ws;             // 256 flags, 64B apart
    float* din = (float*)(ws + 524288);
    us* hdec = (us*)(ws + 526336);
    us* q = (us*)(ws + 1050624);
    us* ctx = (us*)(ws + 1312768);
    us* wiR = (us*)(ws + 1574912);
    float* wi_last = (float*)(ws + 3672064);
    us* whE = (us*)(ws + 3680256);
    us* whD = (us*)(ws + 5777408);
    us* w1B = (us*)(ws + 7874560);
    us* w2B = (us*)(ws + 8398848);
    us* enc_out = (us*)(ws + 8923136);
    us* enc_w1 = (us*)(ws + 42477568);

    __shared__ char bufA[16384];                 // staged A tile (16 batches x 512 bf16)
    __shared__ char bufC[16384];                 // second staging buffer (ctx in Z)
    __shared__ float bufB[2048];                 // gate/q partials
    __shared__ us qbuf[HH];                      // broadcast q row
    __shared__ float scs[LL];
    __shared__ float aj[LL];
    __shared__ float redm[2];
    __shared__ float reds[2];

    const int tid = threadIdx.x;
    const int lane = tid & 63;
    const int w = tid >> 6;                      // wave 0..7
    const int l15 = lane & 15, quad = lane >> 4;
    const int blk = blockIdx.x;
    const int g = blk & 15;
    const int m = blk >> 4;
    const int b0 = g << 4;
    const int myflag = g * 16 + m;
    const int fbase = g * 16;
    const int ct = w & 1;                        // column-tile within block
    const int gate = w >> 1;                     // gate (or k-quarter for Q)
    const int c0 = ((m << 1) | ct) << 4;         // this wave's column base
    unsigned tgt = 0;

    auto stage_contig = [&](const us* src) {     // 16KB contiguous sc1 source -> swizzled bufA
        for (int e = tid; e < 1024; e += 512) {
            int row = e >> 6, bo = (e & 63) << 4;
            bf16x8 v = ldb8_dev(src + (e << 3));
            *(bf16x8*)(bufA + (row << 10) + (bo ^ ((row & 7) << 4))) = v;
        }
    };

    // ---------------- weight converts (cached; fenced barrier publishes) ----------------
    {
        int gt = blk * 512 + tid;
        for (int i = gt; i < H4 * HH; i += 131072) whE[i] = f2bf(enc_Wh[i]);
        for (int i = gt; i < H4 * HH; i += 131072) whD[i] = f2bf(dec_Wh[i]);
        for (int i = gt; i < HH * HH; i += 131072) w1B[i] = f2bf(w1[i]);
        for (int i = gt; i < HH * HH; i += 131072) w2B[i] = f2bf(w2[i]);
        for (int i = gt; i < H4 * HH; i += 131072)
            wiR[i] = f2bf(dec_Wi[(size_t)(i >> 9) * 513 + (i & 511)]);
        if (gt < H4) wi_last[gt] = dec_Wi[(size_t)gt * 513 + 512];
    }
    gsync_f(flags, myflag, ++tgt);

    float creg[4] = {0.f, 0.f, 0.f, 0.f};        // cell state (waves 0,1), encoder -> decoder

    // ---------------- encoder: 128 steps, whE fragments in registers ----------------
    {
        bf16x8 whEf[16];
        {
            const us* Be = whE + (size_t)(gate * HH + c0 + l15) * HH + quad * 8;
#pragma unroll
            for (int kk = 0; kk < 16; ++kk) whEf[kk] = ldb8(Be + kk * 32);
        }
        float biE[4], wiE[4];
        if (w < 2) {
#pragma unroll
            for (int gg = 0; gg < 4; ++gg) {
                int rg = gg * HH + c0 + l15;
                biE[gg] = enc_b[rg];
                wiE[gg] = enc_Wi[rg];
            }
        }
        for (int t = 0; t < LL; ++t) {
            if (t > 0) {
                for (int e = tid; e < 1024; e += 512) {
                    int row = e >> 6, bo = (e & 63) << 4;
                    bf16x8 v = ldb8_dev(enc_out + ((size_t)(b0 + row) * LL + (t - 1)) * HH + (bo >> 1));
                    *(bf16x8*)(bufA + (row << 10) + (bo ^ ((row & 7) << 4))) = v;
                }
                __syncthreads();
                f32x4 acc = {};
#pragma unroll
                for (int kk = 0; kk < 16; ++kk)
                    acc = __builtin_amdgcn_mfma_f32_16x16x32_bf16(ldfragA(bufA, l15, quad, kk),
                                                                  whEf[kk], acc, 0, 0, 0);
#pragma unroll
                for (int r = 0; r < 4; ++r)
                    bufB[(ct * 4 + gate) * 256 + (quad * 4 + r) * 16 + l15] = acc[r];
                __syncthreads();
            }
            if (w < 2) {
#pragma unroll
                for (int r = 0; r < 4; ++r) {
                    int b = b0 + quad * 4 + r;
                    float xv = (float)xs[b * LL + t];
                    float zz[4];
#pragma unroll
                    for (int gg = 0; gg < 4; ++gg)
                        zz[gg] = (t > 0 ? bufB[(w * 4 + gg) * 256 + (quad * 4 + r) * 16 + l15] : 0.f)
                                 + biE[gg] + xv * wiE[gg];
                    float c_ = sigm(zz[1]) * creg[r] + sigm(zz[0]) * tanh_(zz[2]);
                    creg[r] = c_;
                    unsigned hv = (unsigned)f2bf(sigm(zz[3]) * tanh_(c_));
                    st_pair_dev(&enc_out[((size_t)b * LL + t) * HH + c0 + l15], hv, lane);
                    if (t == LL - 1) st_pair_dev(&hdec[(size_t)b * HH + c0 + l15], hv, lane);
                }
            }
            gsync_nf(flags, myflag, fbase, ++tgt);
        }
    }

    // ---------------- enc_w1 = enc_out @ w1^T (cached; fenced publish) ----------------
    {
        int lw = m * 8 + w;
        for (int it = 0; it < 8; ++it) {
            int task = it * 128 + lw;
            int mt = task >> 3;
            int n0 = (task & 7) << 6;
            size_t m0 = (size_t)b0 * LL + (size_t)mt * 16;
            f32x4 acc[4] = {};
            const us* Ar = enc_out + (m0 + l15) * HH + quad * 8;
            const us* Br = w1B + (size_t)(n0 + l15) * HH + quad * 8;
#pragma unroll 8
            for (int kk = 0; kk < 16; ++kk) {
                bf16x8 a = ldb8(Ar + kk * 32);
#pragma unroll
                for (int tt = 0; tt < 4; ++tt) {
                    bf16x8 bv = ldb8(Br + (size_t)tt * 16 * HH + kk * 32);
                    acc[tt] = __builtin_amdgcn_mfma_f32_16x16x32_bf16(a, bv, acc[tt], 0, 0, 0);
                }
            }
#pragma unroll
            for (int tt = 0; tt < 4; ++tt)
#pragma unroll
                for (int r = 0; r < 4; ++r)
                    enc_w1[(m0 + quad * 4 + r) * HH + n0 + tt * 16 + l15] = f2bf(acc[tt][r]);
        }
    }
    gsync_f(flags, myflag, ++tgt);

    // ---------------- per-block residence: enc_w1[b] -> registers ----------------
    bf16x8 ew1f[16];  // thread (w,lane): rows i*8+w, cols lane*8..+7 of enc_w1[b0+m]
    {
        const us* p = enc_w1 + ((size_t)(b0 + m) * LL + w) * HH + lane * 8;
#pragma unroll
        for (int i = 0; i < 16; ++i) ew1f[i] = ldb8(p + (size_t)i * 8 * HH);
    }

    // ---------------- decoder weight fragments into registers (once) ----------------
    bf16x8 wiRf[16], whDf[16], w2f[4];
    {
        const us* Bw = wiR + (size_t)(gate * HH + c0 + l15) * HH + quad * 8;
        const us* Bh = whD + (size_t)(gate * HH + c0 + l15) * HH + quad * 8;
#pragma unroll
        for (int kk = 0; kk < 16; ++kk) {
            wiRf[kk] = ldb8(Bw + kk * 32);
            whDf[kk] = ldb8(Bh + kk * 32);
        }
        const us* Bq = w2B + (size_t)(c0 + l15) * HH + quad * 8;  // wave covers kk = gate*4..+3
#pragma unroll
        for (int j = 0; j < 4; ++j) w2f[j] = ldb8(Bq + (gate * 4 + j) * 32);
    }
    float biD[4], wlD[4];
    if (w < 2) {
#pragma unroll
        for (int gg = 0; gg < 4; ++gg) {
            int rg = gg * HH + c0 + l15;
            biD[gg] = dec_b[rg];
            wlD[gg] = wi_last[rg];
        }
    }
    float vtk[8];  // hoisted: vt is constant across steps
#pragma unroll
    for (int j = 0; j < 8; ++j) vtk[j] = vt[lane * 8 + j];

    // ---------------- decoder: 128 steps ----------------
    for (int t = 0; t < LL; ++t) {
        const us* hcur = hdec + (size_t)(t & 1) * BB * HH;

        // ---- Q: q = h @ w2^T, K split over 8 waves, partials reduced by waves 0,1 ----
        stage_contig(hcur + (size_t)b0 * HH);    // h tile stays in bufA through Z
        __syncthreads();
        {
            f32x4 acc = {};
#pragma unroll
            for (int j = 0; j < 4; ++j)
                acc = __builtin_amdgcn_mfma_f32_16x16x32_bf16(
                    ldfragA(bufA, l15, quad, gate * 4 + j), w2f[j], acc, 0, 0, 0);
#pragma unroll
            for (int r = 0; r < 4; ++r)
                bufB[(gate * 2 + ct) * 256 + (quad * 4 + r) * 16 + l15] = acc[r];
        }
        __syncthreads();
        if (w < 2) {
#pragma unroll
            for (int r = 0; r < 4; ++r) {
                float s = 0.f;
#pragma unroll
                for (int kq = 0; kq < 4; ++kq)
                    s += bufB[(kq * 2 + w) * 256 + (quad * 4 + r) * 16 + l15];
                st_pair_dev(&q[(size_t)(b0 + quad * 4 + r) * HH + c0 + l15],
                            (unsigned)f2bf(s), lane);
            }
        }
        gsync_nf(flags, myflag, fbase, ++tgt);

        // ---- A: attention for batch b0+m (q broadcast via LDS; scores from REGS) ----
        {
            int b = b0 + m;
            if (tid < 64)
                *(bf16x8*)(void*)(qbuf + (tid << 3)) = ldb8_dev(q + (size_t)b * HH + (tid << 3));
            __syncthreads();
            bf16x8 qv = ldb8(qbuf + (lane << 3));
            float qk[8];
#pragma unroll
            for (int j = 0; j < 8; ++j) qk[j] = (float)qv[j];
#pragma unroll 4
            for (int i = 0; i < 16; ++i) {
                int l = i * 8 + w;
                bf16x8 e8 = ew1f[i];
                float s = 0.f;
#pragma unroll
                for (int j = 0; j < 8; ++j) s += tanh_((float)e8[j] + qk[j]) * vtk[j];
#pragma unroll
                for (int off = 1; off < 64; off <<= 1) s += __shfl_xor(s, off);
                if (lane == 0) scs[l] = s;
            }
            __syncthreads();
            bool act = tid < 128;
            float sc = act ? scs[tid] : -1e30f;
            float mx = sc;
#pragma unroll
            for (int off = 1; off < 64; off <<= 1) mx = fmaxf(mx, __shfl_xor(mx, off));
            if (act && lane == 0) redm[w] = mx;
            __syncthreads();
            float M = fmaxf(redm[0], redm[1]);
            float e = act ? __expf(sc - M) : 0.f;
            float ss = e;
#pragma unroll
            for (int off = 1; off < 64; off <<= 1) ss += __shfl_xor(ss, off);
            if (act && lane == 0) reds[w] = ss;
            __syncthreads();
            float S = reds[0] + reds[1];
            if (act) {
                __builtin_nontemporal_store(sc - M - __logf(S), &out[((size_t)b * LL + t) * LL + tid]);
                aj[tid] = e / S;
            }
            __syncthreads();
            // context: plain cached reads of enc_out (L2-resident per XCD)
            const us* ep = enc_out + (size_t)b * LL * HH + tid;
            float cacc = 0.f;
#pragma unroll 16
            for (int l2 = 0; l2 < LL; ++l2) cacc += aj[l2] * bf2f(ep[(size_t)l2 * HH]);
            st_pair_dev(&ctx[(size_t)b * HH + tid], (unsigned)f2bf(cacc), tid & 63);
            if (tid == 0) {
                int idx = argsort[b * LL + t];
                __hip_atomic_store(&din[(size_t)((t + 1) & 1) * BB + b], (float)xs[b * LL + idx],
                                   __ATOMIC_RELAXED, __HIP_MEMORY_SCOPE_AGENT);
            }
        }
        gsync_nf(flags, myflag, fbase, ++tgt);

        // ---- Z: issue ctx loads -> h-part MFMA (latency overlap) -> ctx-part MFMA ----
        {
            // ctx is published (barrier above): issue loads into regs FIRST
            bf16x8 cv0 = ldb8_dev(ctx + (size_t)b0 * HH + (tid << 3));
            bf16x8 cv1 = ldb8_dev(ctx + (size_t)b0 * HH + ((tid + 512) << 3));
            f32x4 zacc = {};
            // h part (bufA still holds h from the Q phase)
#pragma unroll
            for (int kk = 0; kk < 16; ++kk)
                zacc = __builtin_amdgcn_mfma_f32_16x16x32_bf16(ldfragA(bufA, l15, quad, kk),
                                                               whDf[kk], zacc, 0, 0, 0);
            {
                int e = tid, row = e >> 6, bo = (e & 63) << 4;
                *(bf16x8*)(bufC + (row << 10) + (bo ^ ((row & 7) << 4))) = cv0;
                e = tid + 512; row = e >> 6; bo = (e & 63) << 4;
                *(bf16x8*)(bufC + (row << 10) + (bo ^ ((row & 7) << 4))) = cv1;
            }
            __syncthreads();
#pragma unroll
            for (int kk = 0; kk < 16; ++kk)
                zacc = __builtin_amdgcn_mfma_f32_16x16x32_bf16(ldfragA(bufC, l15, quad, kk),
                                                               wiRf[kk], zacc, 0, 0, 0);
#pragma unroll
            for (int r = 0; r < 4; ++r)
                bufB[(ct * 4 + gate) * 256 + (quad * 4 + r) * 16 + l15] = zacc[r];
        }
        __syncthreads();
        if (w < 2) {
            us* hnxt = hdec + (size_t)((t + 1) & 1) * BB * HH;
            const float* dcur = din + (size_t)(t & 1) * BB;
#pragma unroll
            for (int r = 0; r < 4; ++r) {
                int b = b0 + quad * 4 + r;
                float dv = (t == 0) ? 0.f
                                    : __hip_atomic_load((const float*)&dcur[b], __ATOMIC_RELAXED,
                                                        __HIP_MEMORY_SCOPE_AGENT);
                float zz[4];
#pragma unroll
                for (int gg = 0; gg < 4; ++gg)
                    zz[gg] = bufB[(w * 4 + gg) * 256 + (quad * 4 + r) * 16 + l15]
                             + biD[gg] + dv * wlD[gg];
                float c_ = sigm(zz[1]) * creg[r] + sigm(zz[0]) * tanh_(zz[2]);
                creg[r] = c_;
                st_pair_dev(&hnxt[(size_t)b * HH + c0 + l15],
                            (unsigned)f2bf(sigm(zz[3]) * tanh_(c_)), lane);
            }
        }
        gsync_nf(flags, myflag, fbase, ++tgt);
    }
}

extern "C" void kernel_launch(void* const* d_in, const int* in_sizes, int n_in,
                              void* d_out, int out_size, void* d_ws, size_t ws_size,
                              hipStream_t stream) {
    const int* xs = (const int*)d_in[0];
    const int* argsort = (const int*)d_in[2];
    const float* enc_Wi = (const float*)d_in[3];
    const float* enc_Wh = (const float*)d_in[4];
    const float* enc_b = (const float*)d_in[5];
    const float* dec_Wi = (const float*)d_in[6];
    const float* dec_Wh = (const float*)d_in[7];
    const float* dec_b = (const float*)d_in[8];
    const float* w1 = (const float*)d_in[9];
    const float* w2 = (const float*)d_in[10];
    const float* vt = (const float*)d_in[11];
    float* out = (float*)d_out;
    char* ws = (char*)d_ws;

    hipMemsetAsync(ws, 0, 16384, stream);  // 256 flags, 64B apart

    void* kargs[] = {&xs, &argsort, &enc_Wi, &enc_Wh, &enc_b, &dec_Wi, &dec_Wh, &dec_b,
                     &w1, &w2, &vt, &out, &ws};
    hipLaunchCooperativeKernel((void*)k_mega, dim3(256), dim3(512), kargs, 0, stream);

    (void)in_sizes; (void)n_in; (void)out_size; (void)ws_size;
}

// Round 9
// 4864.744 us; speedup vs baseline: 1.7144x; 1.7144x over previous
//
#include <hip/hip_runtime.h>

#define BB 256
#define LL 128
#define HH 512
#define H4 2048

typedef unsigned short us;
typedef unsigned long long u64;
typedef __attribute__((ext_vector_type(8))) __bf16 bf16x8;
typedef __attribute__((ext_vector_type(4))) float f32x4;
typedef __attribute__((ext_vector_type(4))) int i32x4;

__device__ __forceinline__ float bf2f(us s) {
    unsigned u = ((unsigned)s) << 16;
    return __builtin_bit_cast(float, u);
}
__device__ __forceinline__ us f2bf(float f) {
    unsigned u = __builtin_bit_cast(unsigned, f);
    return (us)((u + 0x7fffu + ((u >> 16) & 1u)) >> 16);
}
__device__ __forceinline__ float sigm(float x) { return 1.f / (1.f + __expf(-x)); }
__device__ __forceinline__ float tanh_(float x) { return 1.f - 2.f / (1.f + __expf(2.f * x)); }
__device__ __forceinline__ bf16x8 ldb8(const us* p) { return *(const bf16x8*)(const void*)p; }

// ---- device-coherent (L2-bypassing, sc1) accessors for cross-block recurrent data ----
__device__ __forceinline__ bf16x8 ldb8_dev(const us* p) {
    union { u64 q[2]; bf16x8 v; } u;
    u.q[0] = __hip_atomic_load((const u64*)(const void*)p, __ATOMIC_RELAXED, __HIP_MEMORY_SCOPE_AGENT);
    u.q[1] = __hip_atomic_load((const u64*)(const void*)p + 1, __ATOMIC_RELAXED, __HIP_MEMORY_SCOPE_AGENT);
    return u.v;
}
// lanes (2i,2i+1) hold adjacent bf16 columns of the same row: even lane stores packed 4B
__device__ __forceinline__ void st_pair_dev(us* p, unsigned myv, int lane) {
    unsigned ov = __shfl_xor(myv, 1);
    if (!(lane & 1)) {
        unsigned pk = (myv & 0xffffu) | (ov << 16);
        __hip_atomic_store((unsigned*)(void*)p, pk, __ATOMIC_RELAXED, __HIP_MEMORY_SCOPE_AGENT);
    }
}

// ---- fence-free group barrier (no L2 maintenance) ----
__device__ __forceinline__ void gsync_nf(unsigned* flags, int myidx, int base, int n, unsigned target) {
    __syncthreads();
    if (threadIdx.x < 64) {
        if (threadIdx.x == 0)
            __hip_atomic_store(flags + (size_t)myidx * 16, target, __ATOMIC_RELAXED,
                               __HIP_MEMORY_SCOPE_AGENT);
        for (int i = (int)threadIdx.x; i < n; i += 64)
            while (__hip_atomic_load(flags + (size_t)(base + i) * 16, __ATOMIC_RELAXED,
                                     __HIP_MEMORY_SCOPE_AGENT) < target) {}
        asm volatile("" ::: "memory");
    }
    __syncthreads();
}

// ---- fenced barrier (L2 wb + inv) — used exactly TWICE ----
__device__ __forceinline__ void gsync_f(unsigned* flags, int myidx, int base, int n, unsigned target) {
    __syncthreads();
    if (threadIdx.x < 64) {
        if (threadIdx.x == 0) {
            __builtin_amdgcn_fence(__ATOMIC_RELEASE, "agent");
            __hip_atomic_store(flags + (size_t)myidx * 16, target, __ATOMIC_RELAXED,
                               __HIP_MEMORY_SCOPE_AGENT);
        }
        for (int i = (int)threadIdx.x; i < n; i += 64)
            while (__hip_atomic_load(flags + (size_t)(base + i) * 16, __ATOMIC_RELAXED,
                                     __HIP_MEMORY_SCOPE_AGENT) < target) {}
        __builtin_amdgcn_fence(__ATOMIC_ACQUIRE, "agent");
    }
    __syncthreads();
}

// A-fragment read from the 16x512 bf16 staged tile in LDS (XOR swizzle vs bank conflicts).
__device__ __forceinline__ bf16x8 ldfragA(const char* bufA, int l15, int quad, int kk) {
    int off = ((kk << 6) + (quad << 4)) ^ ((l15 & 7) << 4);
    return *(const bf16x8*)(bufA + (l15 << 10) + off);
}

// Persistent cooperative kernel. Group = 16 blocks (blockIdx & 15).
// Residences: decoder weights + enc_w1[own batch] in REGISTERS; enc_out[own batch] in LDS
// (context source); recurrent h/q/ctx/din via sc1 (MALL); barriers fence-free.
extern "C" __global__ void __launch_bounds__(512) k_mega(
    const int* __restrict__ xs, const int* __restrict__ argsort,
    const float* __restrict__ enc_Wi, const float* __restrict__ enc_Wh, const float* __restrict__ enc_b,
    const float* __restrict__ dec_Wi, const float* __restrict__ dec_Wh, const float* __restrict__ dec_b,
    const float* __restrict__ w1, const float* __restrict__ w2, const float* __restrict__ vt,
    float* __restrict__ out, char* __restrict__ ws) {
    unsigned* flags = (unsigned*)ws;             // 256 * 64B
    float* din = (float*)(ws + 524288);
    us* hdec = (us*)(ws + 526336);
    us* q = (us*)(ws + 1050624);
    us* ctx = (us*)(ws + 1312768);
    us* wiR = (us*)(ws + 1574912);
    float* wi_last = (float*)(ws + 3672064);
    us* whE = (us*)(ws + 3680256);
    us* whD = (us*)(ws + 5777408);
    us* w1B = (us*)(ws + 7874560);
    us* w2B = (us*)(ws + 8398848);
    us* enc_out = (us*)(ws + 8923136);
    us* enc_w1 = (us*)(ws + 42477568);

    extern __shared__ char smem[];
    us* eos = (us*)smem;                         // 131072: enc_out[batch b0+m], [l][h] layout
    char* bufA = smem + 131072;                  // 16384: staged A tile (16 batches x 512 bf16)
    float* bufB = (float*)(smem + 147456);       // 8192: gate/q partials
    __shared__ float scs[LL];
    __shared__ float aj[LL];
    __shared__ float redm[2];
    __shared__ float reds[2];

    const int tid = threadIdx.x;
    const int lane = tid & 63;
    const int w = tid >> 6;                      // wave 0..7
    const int l15 = lane & 15, quad = lane >> 4;
    const int blk = blockIdx.x;
    const int g = blk & 15;
    const int m = blk >> 4;
    const int b0 = g << 4;
    const int myflag = g * 16 + m;
    const int ct = w & 1;                        // column-tile within block
    const int gate = w >> 1;                     // gate (or k-quarter for Q)
    const int c0 = ((m << 1) | ct) << 4;         // this wave's column base
    unsigned tgt = 0;

    auto stage_contig = [&](const us* src) {     // 16KB contiguous sc1 source -> swizzled bufA
        for (int e = tid; e < 1024; e += 512) {
            int row = e >> 6, bo = (e & 63) << 4;
            bf16x8 v = ldb8_dev(src + (e << 3));
            *(bf16x8*)(bufA + (row << 10) + (bo ^ ((row & 7) << 4))) = v;
        }
    };

    // ---------------- weight converts (cached; fenced barrier publishes) ----------------
    {
        int gt = blk * 512 + tid;
        for (int i = gt; i < H4 * HH; i += 131072) whE[i] = f2bf(enc_Wh[i]);
        for (int i = gt; i < H4 * HH; i += 131072) whD[i] = f2bf(dec_Wh[i]);
        for (int i = gt; i < HH * HH; i += 131072) w1B[i] = f2bf(w1[i]);
        for (int i = gt; i < HH * HH; i += 131072) w2B[i] = f2bf(w2[i]);
        for (int i = gt; i < H4 * HH; i += 131072)
            wiR[i] = f2bf(dec_Wi[(size_t)(i >> 9) * 513 + (i & 511)]);
        if (gt < H4) wi_last[gt] = dec_Wi[(size_t)gt * 513 + 512];
    }
    gsync_f(flags, myflag, 0, 256, ++tgt);

    float creg[4] = {0.f, 0.f, 0.f, 0.f};        // cell state (waves 0,1), encoder -> decoder

    // ---------------- encoder: 128 steps, whE fragments in registers ----------------
    {
        bf16x8 whEf[16];
        {
            const us* Be = whE + (size_t)(gate * HH + c0 + l15) * HH + quad * 8;
#pragma unroll
            for (int kk = 0; kk < 16; ++kk) whEf[kk] = ldb8(Be + kk * 32);
        }
        float biE[4], wiE[4];
        if (w < 2) {
#pragma unroll
            for (int gg = 0; gg < 4; ++gg) {
                int rg = gg * HH + c0 + l15;
                biE[gg] = enc_b[rg];
                wiE[gg] = enc_Wi[rg];
            }
        }
        for (int t = 0; t < LL; ++t) {
            if (t > 0) {
                for (int e = tid; e < 1024; e += 512) {
                    int row = e >> 6, bo = (e & 63) << 4;
                    bf16x8 v = ldb8_dev(enc_out + ((size_t)(b0 + row) * LL + (t - 1)) * HH + (bo >> 1));
                    *(bf16x8*)(bufA + (row << 10) + (bo ^ ((row & 7) << 4))) = v;
                }
                __syncthreads();
                f32x4 acc = {};
#pragma unroll
                for (int kk = 0; kk < 16; ++kk)
                    acc = __builtin_amdgcn_mfma_f32_16x16x32_bf16(ldfragA(bufA, l15, quad, kk),
                                                                  whEf[kk], acc, 0, 0, 0);
#pragma unroll
                for (int r = 0; r < 4; ++r)
                    bufB[(ct * 4 + gate) * 256 + (quad * 4 + r) * 16 + l15] = acc[r];
                __syncthreads();
            }
            if (w < 2) {
#pragma unroll
                for (int r = 0; r < 4; ++r) {
                    int b = b0 + quad * 4 + r;
                    float xv = (float)xs[b * LL + t];
                    float zz[4];
#pragma unroll
                    for (int gg = 0; gg < 4; ++gg)
                        zz[gg] = (t > 0 ? bufB[(w * 4 + gg) * 256 + (quad * 4 + r) * 16 + l15] : 0.f)
                                 + biE[gg] + xv * wiE[gg];
                    float c_ = sigm(zz[1]) * creg[r] + sigm(zz[0]) * tanh_(zz[2]);
                    creg[r] = c_;
                    unsigned hv = (unsigned)f2bf(sigm(zz[3]) * tanh_(c_));
                    st_pair_dev(&enc_out[((size_t)b * LL + t) * HH + c0 + l15], hv, lane);
                    if (t == LL - 1) st_pair_dev(&hdec[(size_t)b * HH + c0 + l15], hv, lane);
                }
            }
            gsync_nf(flags, myflag, g * 16, 16, ++tgt);
        }
    }

    // ---------------- enc_w1 = enc_out @ w1^T (cached; fenced group publish) ----------------
    {
        int lw = m * 8 + w;
        for (int it = 0; it < 8; ++it) {
            int task = it * 128 + lw;
            int mt = task >> 3;
            int n0 = (task & 7) << 6;
            size_t m0 = (size_t)b0 * LL + (size_t)mt * 16;
            f32x4 acc[4] = {};
            const us* Ar = enc_out + (m0 + l15) * HH + quad * 8;
            const us* Br = w1B + (size_t)(n0 + l15) * HH + quad * 8;
#pragma unroll 8
            for (int kk = 0; kk < 16; ++kk) {
                bf16x8 a = ldb8(Ar + kk * 32);
#pragma unroll
                for (int tt = 0; tt < 4; ++tt) {
                    bf16x8 bv = ldb8(Br + (size_t)tt * 16 * HH + kk * 32);
                    acc[tt] = __builtin_amdgcn_mfma_f32_16x16x32_bf16(a, bv, acc[tt], 0, 0, 0);
                }
            }
#pragma unroll
            for (int tt = 0; tt < 4; ++tt)
#pragma unroll
                for (int r = 0; r < 4; ++r)
                    enc_w1[(m0 + quad * 4 + r) * HH + n0 + tt * 16 + l15] = f2bf(acc[tt][r]);
        }
    }
    gsync_f(flags, myflag, 0, 256, ++tgt);

    // ---------------- per-block residences: enc_out[b] -> LDS, enc_w1[b] -> registers ----------------
    {
        const i32x4* src = (const i32x4*)(const void*)(enc_out + (size_t)(b0 + m) * LL * HH);
        i32x4* dst = (i32x4*)(void*)eos;
        for (int i = tid; i < 8192; i += 512) dst[i] = src[i];
    }
    bf16x8 ew1f[16];  // thread (w,lane): rows i*8+w, cols lane*8..+7 of enc_w1[b0+m]
    {
        const us* p = enc_w1 + ((size_t)(b0 + m) * LL + w) * HH + lane * 8;
#pragma unroll
        for (int i = 0; i < 16; ++i) ew1f[i] = ldb8(p + (size_t)i * 8 * HH);
    }
    __syncthreads();

    // ---------------- decoder weight fragments into registers (once) ----------------
    bf16x8 wiRf[16], whDf[16], w2f[4];
    {
        const us* Bw = wiR + (size_t)(gate * HH + c0 + l15) * HH + quad * 8;
        const us* Bh = whD + (size_t)(gate * HH + c0 + l15) * HH + quad * 8;
#pragma unroll
        for (int kk = 0; kk < 16; ++kk) {
            wiRf[kk] = ldb8(Bw + kk * 32);
            whDf[kk] = ldb8(Bh + kk * 32);
        }
        const us* Bq = w2B + (size_t)(c0 + l15) * HH + quad * 8;  // wave covers kk = gate*4..+3
#pragma unroll
        for (int j = 0; j < 4; ++j) w2f[j] = ldb8(Bq + (gate * 4 + j) * 32);
    }
    float biD[4], wlD[4];
    if (w < 2) {
#pragma unroll
        for (int gg = 0; gg < 4; ++gg) {
            int rg = gg * HH + c0 + l15;
            biD[gg] = dec_b[rg];
            wlD[gg] = wi_last[rg];
        }
    }

    // ---------------- decoder: 128 steps ----------------
    for (int t = 0; t < LL; ++t) {
        const us* hcur = hdec + (size_t)(t & 1) * BB * HH;

        // ---- Q: q = h @ w2^T, K split over 8 waves, partials reduced by waves 0,1 ----
        stage_contig(hcur + (size_t)b0 * HH);    // h tile stays in bufA through Z
        __syncthreads();
        {
            f32x4 acc = {};
#pragma unroll
            for (int j = 0; j < 4; ++j)
                acc = __builtin_amdgcn_mfma_f32_16x16x32_bf16(
                    ldfragA(bufA, l15, quad, gate * 4 + j), w2f[j], acc, 0, 0, 0);
#pragma unroll
            for (int r = 0; r < 4; ++r)
                bufB[(gate * 2 + ct) * 256 + (quad * 4 + r) * 16 + l15] = acc[r];
        }
        __syncthreads();
        if (w < 2) {
#pragma unroll
            for (int r = 0; r < 4; ++r) {
                float s = 0.f;
#pragma unroll
                for (int kq = 0; kq < 4; ++kq)
                    s += bufB[(kq * 2 + w) * 256 + (quad * 4 + r) * 16 + l15];
                st_pair_dev(&q[(size_t)(b0 + quad * 4 + r) * HH + c0 + l15],
                            (unsigned)f2bf(s), lane);
            }
        }
        gsync_nf(flags, myflag, g * 16, 16, ++tgt);

        // ---- A: attention for batch b0+m (scores from REGS; context from LDS) ----
        {
            int b = b0 + m;
            int k0 = lane * 8;
            bf16x8 qv = ldb8_dev(q + (size_t)b * HH + k0);
            float qk[8], vtk[8];
#pragma unroll
            for (int j = 0; j < 8; ++j) {
                qk[j] = (float)qv[j];
                vtk[j] = vt[k0 + j];
            }
#pragma unroll 4
            for (int i = 0; i < 16; ++i) {
                int l = i * 8 + w;
                bf16x8 e8 = ew1f[i];
                float s = 0.f;
#pragma unroll
                for (int j = 0; j < 8; ++j) s += tanh_((float)e8[j] + qk[j]) * vtk[j];
#pragma unroll
                for (int off = 1; off < 64; off <<= 1) s += __shfl_xor(s, off);
                if (lane == 0) scs[l] = s;
            }
            __syncthreads();
            bool act = tid < 128;
            float sc = act ? scs[tid] : -1e30f;
            float mx = sc;
#pragma unroll
            for (int off = 1; off < 64; off <<= 1) mx = fmaxf(mx, __shfl_xor(mx, off));
            if (act && lane == 0) redm[w] = mx;
            __syncthreads();
            float M = fmaxf(redm[0], redm[1]);
            float e = act ? __expf(sc - M) : 0.f;
            float ss = e;
#pragma unroll
            for (int off = 1; off < 64; off <<= 1) ss += __shfl_xor(ss, off);
            if (act && lane == 0) reds[w] = ss;
            __syncthreads();
            float S = reds[0] + reds[1];
            if (act) {
                __builtin_nontemporal_store(sc - M - __logf(S), &out[((size_t)b * LL + t) * LL + tid]);
                aj[tid] = e / S;
            }
            __syncthreads();
            // context from LDS: addr = l*1024 + tid*2 -> 2-way bank alias (free)
            const us* ep = eos + tid;
            float cacc = 0.f;
#pragma unroll 16
            for (int l2 = 0; l2 < LL; ++l2) cacc += aj[l2] * bf2f(ep[(size_t)l2 * HH]);
            st_pair_dev(&ctx[(size_t)b * HH + tid], (unsigned)f2bf(cacc), tid & 63);
            if (tid == 0) {
                int idx = argsort[b * LL + t];
                __hip_atomic_store(&din[(size_t)((t + 1) & 1) * BB + b], (float)xs[b * LL + idx],
                                   __ATOMIC_RELAXED, __HIP_MEMORY_SCOPE_AGENT);
            }
        }
        gsync_nf(flags, myflag, g * 16, 16, ++tgt);

        // ---- Z: z = [ctx|h] @ W^T + b ; B-fragments in registers, all 8 waves ----
        {
            f32x4 zacc = {};
            // h part first (bufA still holds h from the Q phase)
#pragma unroll
            for (int kk = 0; kk < 16; ++kk)
                zacc = __builtin_amdgcn_mfma_f32_16x16x32_bf16(ldfragA(bufA, l15, quad, kk),
                                                               whDf[kk], zacc, 0, 0, 0);
            __syncthreads();                      // everyone done reading h
            stage_contig(ctx + (size_t)b0 * HH);
            __syncthreads();
#pragma unroll
            for (int kk = 0; kk < 16; ++kk)
                zacc = __builtin_amdgcn_mfma_f32_16x16x32_bf16(ldfragA(bufA, l15, quad, kk),
                                                               wiRf[kk], zacc, 0, 0, 0);
#pragma unroll
            for (int r = 0; r < 4; ++r)
                bufB[(ct * 4 + gate) * 256 + (quad * 4 + r) * 16 + l15] = zacc[r];
        }
        __syncthreads();
        if (w < 2) {
            us* hnxt = hdec + (size_t)((t + 1) & 1) * BB * HH;
            const float* dcur = din + (size_t)(t & 1) * BB;
#pragma unroll
            for (int r = 0; r < 4; ++r) {
                int b = b0 + quad * 4 + r;
                float dv = (t == 0) ? 0.f
                                    : __hip_atomic_load((const float*)&dcur[b], __ATOMIC_RELAXED,
                                                        __HIP_MEMORY_SCOPE_AGENT);
                float zz[4];
#pragma unroll
                for (int gg = 0; gg < 4; ++gg)
                    zz[gg] = bufB[(w * 4 + gg) * 256 + (quad * 4 + r) * 16 + l15]
                             + biD[gg] + dv * wlD[gg];
                float c_ = sigm(zz[1]) * creg[r] + sigm(zz[0]) * tanh_(zz[2]);
                creg[r] = c_;
                st_pair_dev(&hnxt[(size_t)b * HH + c0 + l15],
                            (unsigned)f2bf(sigm(zz[3]) * tanh_(c_)), lane);
            }
        }
        gsync_nf(flags, myflag, g * 16, 16, ++tgt);
    }
}

extern "C" void kernel_launch(void* const* d_in, const int* in_sizes, int n_in,
                              void* d_out, int out_size, void* d_ws, size_t ws_size,
                              hipStream_t stream) {
    const int* xs = (const int*)d_in[0];
    const int* argsort = (const int*)d_in[2];
    const float* enc_Wi = (const float*)d_in[3];
    const float* enc_Wh = (const float*)d_in[4];
    const float* enc_b = (const float*)d_in[5];
    const float* dec_Wi = (const float*)d_in[6];
    const float* dec_Wh = (const float*)d_in[7];
    const float* dec_b = (const float*)d_in[8];
    const float* w1 = (const float*)d_in[9];
    const float* w2 = (const float*)d_in[10];
    const float* vt = (const float*)d_in[11];
    float* out = (float*)d_out;
    char* ws = (char*)d_ws;

    static bool attr_done = false;
    if (!attr_done) {
        hipFuncSetAttribute((const void*)k_mega, hipFuncAttributeMaxDynamicSharedMemorySize, 155648);
        attr_done = true;
    }

    hipMemsetAsync(ws, 0, 16384, stream);

    void* kargs[] = {&xs, &argsort, &enc_Wi, &enc_Wh, &enc_b, &dec_Wi, &dec_Wh, &dec_b,
                     &w1, &w2, &vt, &out, &ws};
    hipLaunchCooperativeKernel((void*)k_mega, dim3(256), dim3(512), kargs, 155648, stream);

    (void)in_sizes; (void)n_in; (void)out_size; (void)ws_size;
}

// Round 12
// 4482.121 us; speedup vs baseline: 1.8607x; 1.0854x over previous
//
#include <hip/hip_runtime.h>

#define BB 256
#define LL 128
#define HH 512
#define H4 2048

typedef unsigned short us;
typedef unsigned long long u64;
typedef __attribute__((ext_vector_type(8))) __bf16 bf16x8;
typedef __attribute__((ext_vector_type(4))) float f32x4;
typedef __attribute__((ext_vector_type(4))) int i32x4;

__device__ __forceinline__ float bf2f(us s) {
    unsigned u = ((unsigned)s) << 16;
    return __builtin_bit_cast(float, u);
}
__device__ __forceinline__ us f2bf(float f) {
    unsigned u = __builtin_bit_cast(unsigned, f);
    return (us)((u + 0x7fffu + ((u >> 16) & 1u)) >> 16);
}
__device__ __forceinline__ float sigm(float x) { return 1.f / (1.f + __expf(-x)); }
__device__ __forceinline__ float tanh_(float x) { return 1.f - 2.f / (1.f + __expf(2.f * x)); }
__device__ __forceinline__ bf16x8 ldb8(const us* p) { return *(const bf16x8*)(const void*)p; }

// ---- device-coherent (L2-bypassing, sc1) accessors for cross-block recurrent data ----
__device__ __forceinline__ bf16x8 ldb8_dev(const us* p) {
    union { u64 q[2]; bf16x8 v; } u;
    u.q[0] = __hip_atomic_load((const u64*)(const void*)p, __ATOMIC_RELAXED, __HIP_MEMORY_SCOPE_AGENT);
    u.q[1] = __hip_atomic_load((const u64*)(const void*)p + 1, __ATOMIC_RELAXED, __HIP_MEMORY_SCOPE_AGENT);
    return u.v;
}
// lanes (2i,2i+1) hold adjacent bf16 columns of the same row: even lane stores packed 4B
__device__ __forceinline__ void st_pair_dev(us* p, unsigned myv, int lane) {
    unsigned ov = __shfl_xor(myv, 1);
    if (!(lane & 1)) {
        unsigned pk = (myv & 0xffffu) | (ov << 16);
        __hip_atomic_store((unsigned*)(void*)p, pk, __ATOMIC_RELAXED, __HIP_MEMORY_SCOPE_AGENT);
    }
}

// ---- fence-free group barrier (r5/r9-proven): flag per block on its OWN 64B line ----
__device__ __forceinline__ void gsync_nf(unsigned* flags, int myidx, int base, int n, unsigned target) {
    __syncthreads();
    if (threadIdx.x < 64) {
        if (threadIdx.x == 0)
            __hip_atomic_store(flags + (size_t)myidx * 16, target, __ATOMIC_RELAXED,
                               __HIP_MEMORY_SCOPE_AGENT);
        for (int i = (int)threadIdx.x; i < n; i += 64)
            while (__hip_atomic_load(flags + (size_t)(base + i) * 16, __ATOMIC_RELAXED,
                                     __HIP_MEMORY_SCOPE_AGENT) < target) {}
        asm volatile("" ::: "memory");
    }
    __syncthreads();
}

// ---- fenced barrier (L2 wb + inv) — used exactly TWICE ----
__device__ __forceinline__ void gsync_f(unsigned* flags, int myidx, int base, int n, unsigned target) {
    __syncthreads();
    if (threadIdx.x < 64) {
        if (threadIdx.x == 0) {
            __builtin_amdgcn_fence(__ATOMIC_RELEASE, "agent");
            __hip_atomic_store(flags + (size_t)myidx * 16, target, __ATOMIC_RELAXED,
                               __HIP_MEMORY_SCOPE_AGENT);
        }
        for (int i = (int)threadIdx.x; i < n; i += 64)
            while (__hip_atomic_load(flags + (size_t)(base + i) * 16, __ATOMIC_RELAXED,
                                     __HIP_MEMORY_SCOPE_AGENT) < target) {}
        __builtin_amdgcn_fence(__ATOMIC_ACQUIRE, "agent");
    }
    __syncthreads();
}

// A-fragment read from the 16x512 bf16 staged tile in LDS (XOR swizzle vs bank conflicts).
__device__ __forceinline__ bf16x8 ldfragA(const char* bufA, int l15, int quad, int kk) {
    int off = ((kk << 6) + (quad << 4)) ^ ((l15 & 7) << 4);
    return *(const bf16x8*)(bufA + (l15 << 10) + off);
}

// Persistent cooperative kernel. Group = 16 blocks (blockIdx & 15).
// Residences: decoder weights + enc_w1[own batch] in REGISTERS; enc_out[own batch] in LDS
// (context source); recurrent h/q/ctx/din via sc1 (MALL); barriers fence-free.
extern "C" __global__ void __launch_bounds__(512) k_mega(
    const int* __restrict__ xs, const int* __restrict__ argsort,
    const float* __restrict__ enc_Wi, const float* __restrict__ enc_Wh, const float* __restrict__ enc_b,
    const float* __restrict__ dec_Wi, const float* __restrict__ dec_Wh, const float* __restrict__ dec_b,
    const float* __restrict__ w1, const float* __restrict__ w2, const float* __restrict__ vt,
    float* __restrict__ out, char* __restrict__ ws) {
    unsigned* flags = (unsigned*)ws;             // 256 * 64B
    float* din = (float*)(ws + 524288);
    us* hdec = (us*)(ws + 526336);
    us* q = (us*)(ws + 1050624);
    us* ctx = (us*)(ws + 1312768);
    us* wiR = (us*)(ws + 1574912);
    float* wi_last = (float*)(ws + 3672064);
    us* whE = (us*)(ws + 3680256);
    us* whD = (us*)(ws + 5777408);
    us* w1B = (us*)(ws + 7874560);
    us* w2B = (us*)(ws + 8398848);
    us* enc_out = (us*)(ws + 8923136);
    us* enc_w1 = (us*)(ws + 42477568);

    extern __shared__ char smem[];
    us* eos = (us*)smem;                         // 131072: enc_out[batch b0+m], [l][h] layout
    char* bufA = smem + 131072;                  // 16384: staged A tile (16 batches x 512 bf16)
    float* bufB = (float*)(smem + 147456);       // 8192: gate/q partials
    __shared__ us qbuf[HH];                      // broadcast q row (1KB, loaded once not 8x)
    __shared__ float scs[LL];
    __shared__ float aj[LL];
    __shared__ float redm[2];
    __shared__ float reds[2];

    const int tid = threadIdx.x;
    const int lane = tid & 63;
    const int w = tid >> 6;                      // wave 0..7
    const int l15 = lane & 15, quad = lane >> 4;
    const int blk = blockIdx.x;
    const int g = blk & 15;
    const int m = blk >> 4;
    const int b0 = g << 4;
    const int myflag = g * 16 + m;
    const int ct = w & 1;                        // column-tile within block
    const int gate = w >> 1;                     // gate (or k-quarter for Q)
    const int c0 = ((m << 1) | ct) << 4;         // this wave's column base
    unsigned tgt = 0;

    auto stage_contig = [&](const us* src) {     // 16KB contiguous sc1 source -> swizzled bufA
        for (int e = tid; e < 1024; e += 512) {
            int row = e >> 6, bo = (e & 63) << 4;
            bf16x8 v = ldb8_dev(src + (e << 3));
            *(bf16x8*)(bufA + (row << 10) + (bo ^ ((row & 7) << 4))) = v;
        }
    };

    // ---------------- weight converts (cached; fenced barrier publishes) ----------------
    {
        int gt = blk * 512 + tid;
        for (int i = gt; i < H4 * HH; i += 131072) whE[i] = f2bf(enc_Wh[i]);
        for (int i = gt; i < H4 * HH; i += 131072) whD[i] = f2bf(dec_Wh[i]);
        for (int i = gt; i < HH * HH; i += 131072) w1B[i] = f2bf(w1[i]);
        for (int i = gt; i < HH * HH; i += 131072) w2B[i] = f2bf(w2[i]);
        for (int i = gt; i < H4 * HH; i += 131072)
            wiR[i] = f2bf(dec_Wi[(size_t)(i >> 9) * 513 + (i & 511)]);
        if (gt < H4) wi_last[gt] = dec_Wi[(size_t)gt * 513 + 512];
    }
    gsync_f(flags, myflag, 0, 256, ++tgt);

    float creg[4] = {0.f, 0.f, 0.f, 0.f};        // cell state (waves 0,1), encoder -> decoder

    // ---------------- encoder: 128 steps, whE fragments in registers ----------------
    {
        bf16x8 whEf[16];
        {
            const us* Be = whE + (size_t)(gate * HH + c0 + l15) * HH + quad * 8;
#pragma unroll
            for (int kk = 0; kk < 16; ++kk) whEf[kk] = ldb8(Be + kk * 32);
        }
        float biE[4], wiE[4];
        if (w < 2) {
#pragma unroll
            for (int gg = 0; gg < 4; ++gg) {
                int rg = gg * HH + c0 + l15;
                biE[gg] = enc_b[rg];
                wiE[gg] = enc_Wi[rg];
            }
        }
        for (int t = 0; t < LL; ++t) {
            if (t > 0) {
                for (int e = tid; e < 1024; e += 512) {
                    int row = e >> 6, bo = (e & 63) << 4;
                    bf16x8 v = ldb8_dev(enc_out + ((size_t)(b0 + row) * LL + (t - 1)) * HH + (bo >> 1));
                    *(bf16x8*)(bufA + (row << 10) + (bo ^ ((row & 7) << 4))) = v;
                }
                __syncthreads();
                f32x4 acc = {};
#pragma unroll
                for (int kk = 0; kk < 16; ++kk)
                    acc = __builtin_amdgcn_mfma_f32_16x16x32_bf16(ldfragA(bufA, l15, quad, kk),
                                                                  whEf[kk], acc, 0, 0, 0);
#pragma unroll
                for (int r = 0; r < 4; ++r)
                    bufB[(ct * 4 + gate) * 256 + (quad * 4 + r) * 16 + l15] = acc[r];
                __syncthreads();
            }
            if (w < 2) {
#pragma unroll
                for (int r = 0; r < 4; ++r) {
                    int b = b0 + quad * 4 + r;
                    float xv = (float)xs[b * LL + t];
                    float zz[4];
#pragma unroll
                    for (int gg = 0; gg < 4; ++gg)
                        zz[gg] = (t > 0 ? bufB[(w * 4 + gg) * 256 + (quad * 4 + r) * 16 + l15] : 0.f)
                                 + biE[gg] + xv * wiE[gg];
                    float c_ = sigm(zz[1]) * creg[r] + sigm(zz[0]) * tanh_(zz[2]);
                    creg[r] = c_;
                    unsigned hv = (unsigned)f2bf(sigm(zz[3]) * tanh_(c_));
                    st_pair_dev(&enc_out[((size_t)b * LL + t) * HH + c0 + l15], hv, lane);
                    if (t == LL - 1) st_pair_dev(&hdec[(size_t)b * HH + c0 + l15], hv, lane);
                }
            }
            gsync_nf(flags, myflag, g * 16, 16, ++tgt);
        }
    }

    // ---------------- enc_w1 = enc_out @ w1^T (cached; fenced group publish) ----------------
    {
        int lw = m * 8 + w;
        for (int it = 0; it < 8; ++it) {
            int task = it * 128 + lw;
            int mt = task >> 3;
            int n0 = (task & 7) << 6;
            size_t m0 = (size_t)b0 * LL + (size_t)mt * 16;
            f32x4 acc[4] = {};
            const us* Ar = enc_out + (m0 + l15) * HH + quad * 8;
            const us* Br = w1B + (size_t)(n0 + l15) * HH + quad * 8;
#pragma unroll 8
            for (int kk = 0; kk < 16; ++kk) {
                bf16x8 a = ldb8(Ar + kk * 32);
#pragma unroll
                for (int tt = 0; tt < 4; ++tt) {
                    bf16x8 bv = ldb8(Br + (size_t)tt * 16 * HH + kk * 32);
                    acc[tt] = __builtin_amdgcn_mfma_f32_16x16x32_bf16(a, bv, acc[tt], 0, 0, 0);
                }
            }
#pragma unroll
            for (int tt = 0; tt < 4; ++tt)
#pragma unroll
                for (int r = 0; r < 4; ++r)
                    enc_w1[(m0 + quad * 4 + r) * HH + n0 + tt * 16 + l15] = f2bf(acc[tt][r]);
        }
    }
    gsync_f(flags, myflag, 0, 256, ++tgt);

    // ---------------- per-block residences: enc_out[b] -> LDS, enc_w1[b] -> registers ----------------
    {
        const i32x4* src = (const i32x4*)(const void*)(enc_out + (size_t)(b0 + m) * LL * HH);
        i32x4* dst = (i32x4*)(void*)eos;
        for (int i = tid; i < 8192; i += 512) dst[i] = src[i];
    }
    bf16x8 ew1f[16];  // thread (w,lane): rows i*8+w, cols lane*8..+7 of enc_w1[b0+m]
    {
        const us* p = enc_w1 + ((size_t)(b0 + m) * LL + w) * HH + lane * 8;
#pragma unroll
        for (int i = 0; i < 16; ++i) ew1f[i] = ldb8(p + (size_t)i * 8 * HH);
    }
    __syncthreads();

    // ---------------- decoder weight fragments into registers (once) ----------------
    bf16x8 wiRf[16], whDf[16], w2f[4];
    {
        const us* Bw = wiR + (size_t)(gate * HH + c0 + l15) * HH + quad * 8;
        const us* Bh = whD + (size_t)(gate * HH + c0 + l15) * HH + quad * 8;
#pragma unroll
        for (int kk = 0; kk < 16; ++kk) {
            wiRf[kk] = ldb8(Bw + kk * 32);
            whDf[kk] = ldb8(Bh + kk * 32);
        }
        const us* Bq = w2B + (size_t)(c0 + l15) * HH + quad * 8;  // wave covers kk = gate*4..+3
#pragma unroll
        for (int j = 0; j < 4; ++j) w2f[j] = ldb8(Bq + (gate * 4 + j) * 32);
    }
    float biD[4], wlD[4];
    if (w < 2) {
#pragma unroll
        for (int gg = 0; gg < 4; ++gg) {
            int rg = gg * HH + c0 + l15;
            biD[gg] = dec_b[rg];
            wlD[gg] = wi_last[rg];
        }
    }
    float vtk[8];  // hoisted: vt is constant across steps
#pragma unroll
    for (int j = 0; j < 8; ++j) vtk[j] = vt[lane * 8 + j];

    // ---------------- decoder: 128 steps ----------------
    for (int t = 0; t < LL; ++t) {
        const us* hcur = hdec + (size_t)(t & 1) * BB * HH;

        // ---- Q: q = h @ w2^T, K split over 8 waves, partials reduced by waves 0,1 ----
        stage_contig(hcur + (size_t)b0 * HH);    // h tile stays in bufA through Z's h-MFMA
        __syncthreads();
        {
            f32x4 acc = {};
#pragma unroll
            for (int j = 0; j < 4; ++j)
                acc = __builtin_amdgcn_mfma_f32_16x16x32_bf16(
                    ldfragA(bufA, l15, quad, gate * 4 + j), w2f[j], acc, 0, 0, 0);
#pragma unroll
            for (int r = 0; r < 4; ++r)
                bufB[(gate * 2 + ct) * 256 + (quad * 4 + r) * 16 + l15] = acc[r];
        }
        __syncthreads();
        if (w < 2) {
#pragma unroll
            for (int r = 0; r < 4; ++r) {
                float s = 0.f;
#pragma unroll
                for (int kq = 0; kq < 4; ++kq)
                    s += bufB[(kq * 2 + w) * 256 + (quad * 4 + r) * 16 + l15];
                st_pair_dev(&q[(size_t)(b0 + quad * 4 + r) * HH + c0 + l15],
                            (unsigned)f2bf(s), lane);
            }
        }
        gsync_nf(flags, myflag, g * 16, 16, ++tgt);

        // ---- A: attention for batch b0+m (q deduped via LDS; scores from REGS; ctx from LDS) ----
        {
            int b = b0 + m;
            if (tid < 64)
                *(bf16x8*)(void*)(qbuf + (tid << 3)) = ldb8_dev(q + (size_t)b * HH + (tid << 3));
            __syncthreads();
            bf16x8 qv = ldb8(qbuf + (lane << 3));
            float qk[8];
#pragma unroll
            for (int j = 0; j < 8; ++j) qk[j] = (float)qv[j];
#pragma unroll 4
            for (int i = 0; i < 16; ++i) {
                int l = i * 8 + w;
                bf16x8 e8 = ew1f[i];
                float s = 0.f;
#pragma unroll
                for (int j = 0; j < 8; ++j) s += tanh_((float)e8[j] + qk[j]) * vtk[j];
#pragma unroll
                for (int off = 1; off < 64; off <<= 1) s += __shfl_xor(s, off);
                if (lane == 0) scs[l] = s;
            }
            __syncthreads();
            bool act = tid < 128;
            float sc = act ? scs[tid] : -1e30f;
            float mx = sc;
#pragma unroll
            for (int off = 1; off < 64; off <<= 1) mx = fmaxf(mx, __shfl_xor(mx, off));
            if (act && lane == 0) redm[w] = mx;
            __syncthreads();
            float M = fmaxf(redm[0], redm[1]);
            float e = act ? __expf(sc - M) : 0.f;
            float ss = e;
#pragma unroll
            for (int off = 1; off < 64; off <<= 1) ss += __shfl_xor(ss, off);
            if (act && lane == 0) reds[w] = ss;
            __syncthreads();
            float S = reds[0] + reds[1];
            if (act) {
                __builtin_nontemporal_store(sc - M - __logf(S), &out[((size_t)b * LL + t) * LL + tid]);
                aj[tid] = e / S;
            }
            __syncthreads();
            // context from LDS: addr = l*1024 + tid*2 -> 2-way bank alias (free)
            const us* ep = eos + tid;
            float cacc = 0.f;
#pragma unroll 16
            for (int l2 = 0; l2 < LL; ++l2) cacc += aj[l2] * bf2f(ep[(size_t)l2 * HH]);
            st_pair_dev(&ctx[(size_t)b * HH + tid], (unsigned)f2bf(cacc), tid & 63);
            if (tid == 0) {
                int idx = argsort[b * LL + t];
                __hip_atomic_store(&din[(size_t)((t + 1) & 1) * BB + b], (float)xs[b * LL + idx],
                                   __ATOMIC_RELAXED, __HIP_MEMORY_SCOPE_AGENT);
            }
        }
        gsync_nf(flags, myflag, g * 16, 16, ++tgt);

        // ---- Z: issue ctx loads early (hide sc1 latency under h-MFMA) -> ctx-MFMA ----
        {
            bf16x8 cv0 = ldb8_dev(ctx + (size_t)b0 * HH + (tid << 3));
            bf16x8 cv1 = ldb8_dev(ctx + (size_t)b0 * HH + ((size_t)(tid + 512) << 3));
            f32x4 zacc = {};
            // h part (bufA still holds h from the Q phase); ctx loads in flight
#pragma unroll
            for (int kk = 0; kk < 16; ++kk)
                zacc = __builtin_amdgcn_mfma_f32_16x16x32_bf16(ldfragA(bufA, l15, quad, kk),
                                                               whDf[kk], zacc, 0, 0, 0);
            __syncthreads();                      // everyone done reading h from bufA
            {
                int e = tid, row = e >> 6, bo = (e & 63) << 4;
                *(bf16x8*)(bufA + (row << 10) + (bo ^ ((row & 7) << 4))) = cv0;
                e = tid + 512; row = e >> 6; bo = (e & 63) << 4;
                *(bf16x8*)(bufA + (row << 10) + (bo ^ ((row & 7) << 4))) = cv1;
            }
            __syncthreads();
#pragma unroll
            for (int kk = 0; kk < 16; ++kk)
                zacc = __builtin_amdgcn_mfma_f32_16x16x32_bf16(ldfragA(bufA, l15, quad, kk),
                                                               wiRf[kk], zacc, 0, 0, 0);
#pragma unroll
            for (int r = 0; r < 4; ++r)
                bufB[(ct * 4 + gate) * 256 + (quad * 4 + r) * 16 + l15] = zacc[r];
        }
        __syncthreads();
        if (w < 2) {
            us* hnxt = hdec + (size_t)((t + 1) & 1) * BB * HH;
            const float* dcur = din + (size_t)(t & 1) * BB;
#pragma unroll
            for (int r = 0; r < 4; ++r) {
                int b = b0 + quad * 4 + r;
                float dv = (t == 0) ? 0.f
                                    : __hip_atomic_load((const float*)&dcur[b], __ATOMIC_RELAXED,
                                                        __HIP_MEMORY_SCOPE_AGENT);
                float zz[4];
#pragma unroll
                for (int gg = 0; gg < 4; ++gg)
                    zz[gg] = bufB[(w * 4 + gg) * 256 + (quad * 4 + r) * 16 + l15]
                             + biD[gg] + dv * wlD[gg];
                float c_ = sigm(zz[1]) * creg[r] + sigm(zz[0]) * tanh_(zz[2]);
                creg[r] = c_;
                st_pair_dev(&hnxt[(size_t)b * HH + c0 + l15],
                            (unsigned)f2bf(sigm(zz[3]) * tanh_(c_)), lane);
            }
        }
        gsync_nf(flags, myflag, g * 16, 16, ++tgt);
    }
}

extern "C" void kernel_launch(void* const* d_in, const int* in_sizes, int n_in,
                              void* d_out, int out_size, void* d_ws, size_t ws_size,
                              hipStream_t stream) {
    const int* xs = (const int*)d_in[0];
    const int* argsort = (const int*)d_in[2];
    const float* enc_Wi = (const float*)d_in[3];
    const float* enc_Wh = (const float*)d_in[4];
    const float* enc_b = (const float*)d_in[5];
    const float* dec_Wi = (const float*)d_in[6];
    const float* dec_Wh = (const float*)d_in[7];
    const float* dec_b = (const float*)d_in[8];
    const float* w1 = (const float*)d_in[9];
    const float* w2 = (const float*)d_in[10];
    const float* vt = (const float*)d_in[11];
    float* out = (float*)d_out;
    char* ws = (char*)d_ws;

    static bool attr_done = false;
    if (!attr_done) {
        hipFuncSetAttribute((const void*)k_mega, hipFuncAttributeMaxDynamicSharedMemorySize, 155648);
        attr_done = true;
    }

    hipMemsetAsync(ws, 0, 16384, stream);

    void* kargs[] = {&xs, &argsort, &enc_Wi, &enc_Wh, &enc_b, &dec_Wi, &dec_Wh, &dec_b,
                     &w1, &w2, &vt, &out, &ws};
    hipLaunchCooperativeKernel((void*)k_mega, dim3(256), dim3(512), kargs, 155648, stream);

    (void)in_sizes; (void)n_in; (void)out_size; (void)ws_size;
}

// Round 13
// 4300.068 us; speedup vs baseline: 1.9395x; 1.0423x over previous
//
#include <hip/hip_runtime.h>

#define BB 256
#define LL 128
#define HH 512
#define H4 2048

typedef unsigned short us;
typedef unsigned long long u64;
typedef __attribute__((ext_vector_type(8))) __bf16 bf16x8;
typedef __attribute__((ext_vector_type(4))) float f32x4;
typedef __attribute__((ext_vector_type(4))) int i32x4;

__device__ __forceinline__ float bf2f(us s) {
    unsigned u = ((unsigned)s) << 16;
    return __builtin_bit_cast(float, u);
}
__device__ __forceinline__ us f2bf(float f) {
    unsigned u = __builtin_bit_cast(unsigned, f);
    return (us)((u + 0x7fffu + ((u >> 16) & 1u)) >> 16);
}
__device__ __forceinline__ float sigm(float x) { return 1.f / (1.f + __expf(-x)); }
__device__ __forceinline__ float tanh_(float x) { return 1.f - 2.f / (1.f + __expf(2.f * x)); }
__device__ __forceinline__ bf16x8 ldb8(const us* p) { return *(const bf16x8*)(const void*)p; }

// ---- device-coherent (L2-bypassing, sc1) accessors for cross-block recurrent data ----
__device__ __forceinline__ bf16x8 ldb8_dev(const us* p) {
    union { u64 q[2]; bf16x8 v; } u;
    u.q[0] = __hip_atomic_load((const u64*)(const void*)p, __ATOMIC_RELAXED, __HIP_MEMORY_SCOPE_AGENT);
    u.q[1] = __hip_atomic_load((const u64*)(const void*)p + 1, __ATOMIC_RELAXED, __HIP_MEMORY_SCOPE_AGENT);
    return u.v;
}
// lanes (2i,2i+1) hold adjacent bf16 columns of the same row: even lane stores packed 4B
__device__ __forceinline__ void st_pair_dev(us* p, unsigned myv, int lane) {
    unsigned ov = __shfl_xor(myv, 1);
    if (!(lane & 1)) {
        unsigned pk = (myv & 0xffffu) | (ov << 16);
        __hip_atomic_store((unsigned*)(void*)p, pk, __ATOMIC_RELAXED, __HIP_MEMORY_SCOPE_AGENT);
    }
}

// ---- fence-free group barrier (r5/r9-proven): flag per block on its OWN 64B line ----
__device__ __forceinline__ void gsync_nf(unsigned* flags, int myidx, int base, int n, unsigned target) {
    __syncthreads();
    if (threadIdx.x < 64) {
        if (threadIdx.x == 0)
            __hip_atomic_store(flags + (size_t)myidx * 16, target, __ATOMIC_RELAXED,
                               __HIP_MEMORY_SCOPE_AGENT);
        for (int i = (int)threadIdx.x; i < n; i += 64)
            while (__hip_atomic_load(flags + (size_t)(base + i) * 16, __ATOMIC_RELAXED,
                                     __HIP_MEMORY_SCOPE_AGENT) < target) {}
        asm volatile("" ::: "memory");
    }
    __syncthreads();
}

// ---- fenced barrier (L2 wb + inv) — used exactly TWICE ----
__device__ __forceinline__ void gsync_f(unsigned* flags, int myidx, int base, int n, unsigned target) {
    __syncthreads();
    if (threadIdx.x < 64) {
        if (threadIdx.x == 0) {
            __builtin_amdgcn_fence(__ATOMIC_RELEASE, "agent");
            __hip_atomic_store(flags + (size_t)myidx * 16, target, __ATOMIC_RELAXED,
                               __HIP_MEMORY_SCOPE_AGENT);
        }
        for (int i = (int)threadIdx.x; i < n; i += 64)
            while (__hip_atomic_load(flags + (size_t)(base + i) * 16, __ATOMIC_RELAXED,
                                     __HIP_MEMORY_SCOPE_AGENT) < target) {}
        __builtin_amdgcn_fence(__ATOMIC_ACQUIRE, "agent");
    }
    __syncthreads();
}

// A-fragment read from the 16x512 bf16 staged tile in LDS (XOR swizzle vs bank conflicts).
__device__ __forceinline__ bf16x8 ldfragA(const char* bufA, int l15, int quad, int kk) {
    int off = ((kk << 6) + (quad << 4)) ^ ((l15 & 7) << 4);
    return *(const bf16x8*)(bufA + (l15 << 10) + off);
}

// Persistent cooperative kernel. Group = 16 blocks (blockIdx & 15).
// Residences: decoder weights + enc_w1[own batch] in REGISTERS; enc_out[own batch] in LDS
// (context source); recurrent h/q/ctx via sc1 (MALL); teacher-forcing inputs precomputed
// into an L2-cached table (no recurrent dependency); barriers fence-free.
extern "C" __global__ void __launch_bounds__(512) k_mega(
    const int* __restrict__ xs, const int* __restrict__ argsort,
    const float* __restrict__ enc_Wi, const float* __restrict__ enc_Wh, const float* __restrict__ enc_b,
    const float* __restrict__ dec_Wi, const float* __restrict__ dec_Wh, const float* __restrict__ dec_b,
    const float* __restrict__ w1, const float* __restrict__ w2, const float* __restrict__ vt,
    float* __restrict__ out, char* __restrict__ ws) {
    unsigned* flags = (unsigned*)ws;             // 256 * 64B
    float* dint = (float*)(ws + 16384);          // [128][256] teacher-forcing table (131072 B)
    us* hdec = (us*)(ws + 526336);
    us* q = (us*)(ws + 1050624);
    us* ctx = (us*)(ws + 1312768);
    us* wiR = (us*)(ws + 1574912);
    float* wi_last = (float*)(ws + 3672064);
    us* whE = (us*)(ws + 3680256);
    us* whD = (us*)(ws + 5777408);
    us* w1B = (us*)(ws + 7874560);
    us* w2B = (us*)(ws + 8398848);
    us* enc_out = (us*)(ws + 8923136);
    us* enc_w1 = (us*)(ws + 42477568);

    extern __shared__ char smem[];
    us* eos = (us*)smem;                         // 131072: enc_out[batch b0+m], [l][h] layout
    char* bufA = smem + 131072;                  // 16384: staged A tile (16 batches x 512 bf16)
    float* bufB = (float*)(smem + 147456);       // 8192: gate/q partials
    __shared__ us qbuf[HH];                      // broadcast q row (1KB, loaded once not 8x)
    __shared__ float scs[LL];
    __shared__ float aj[LL];
    __shared__ float redm[2];
    __shared__ float reds[2];

    const int tid = threadIdx.x;
    const int lane = tid & 63;
    const int w = tid >> 6;                      // wave 0..7
    const int l15 = lane & 15, quad = lane >> 4;
    const int blk = blockIdx.x;
    const int g = blk & 15;
    const int m = blk >> 4;
    const int b0 = g << 4;
    const int myflag = g * 16 + m;
    const int ct = w & 1;                        // column-tile within block
    const int gate = w >> 1;                     // gate (or k-quarter for Q)
    const int c0 = ((m << 1) | ct) << 4;         // this wave's column base
    unsigned tgt = 0;

    auto stage_contig = [&](const us* src) {     // 16KB contiguous sc1 source -> swizzled bufA
        for (int e = tid; e < 1024; e += 512) {
            int row = e >> 6, bo = (e & 63) << 4;
            bf16x8 v = ldb8_dev(src + (e << 3));
            *(bf16x8*)(bufA + (row << 10) + (bo ^ ((row & 7) << 4))) = v;
        }
    };

    // ---------------- weight converts + TF table (cached; fenced barrier publishes) ----------------
    {
        int gt = blk * 512 + tid;
        for (int i = gt; i < H4 * HH; i += 131072) whE[i] = f2bf(enc_Wh[i]);
        for (int i = gt; i < H4 * HH; i += 131072) whD[i] = f2bf(dec_Wh[i]);
        for (int i = gt; i < HH * HH; i += 131072) w1B[i] = f2bf(w1[i]);
        for (int i = gt; i < HH * HH; i += 131072) w2B[i] = f2bf(w2[i]);
        for (int i = gt; i < H4 * HH; i += 131072)
            wiR[i] = f2bf(dec_Wi[(size_t)(i >> 9) * 513 + (i & 511)]);
        if (gt < H4) wi_last[gt] = dec_Wi[(size_t)gt * 513 + 512];
        // teacher-forcing inputs: dint[t][b] = t==0 ? 0 : xs[b][argsort[b][t-1]]
        if (gt < LL * BB) {
            int tt = gt >> 8, b = gt & 255;
            dint[gt] = (tt == 0) ? 0.f
                                 : (float)xs[b * LL + argsort[b * LL + tt - 1]];
        }
    }
    gsync_f(flags, myflag, 0, 256, ++tgt);

    float creg[4] = {0.f, 0.f, 0.f, 0.f};        // cell state (waves 0,1), encoder -> decoder

    // ---------------- encoder: 128 steps, whE fragments in registers ----------------
    {
        bf16x8 whEf[16];
        {
            const us* Be = whE + (size_t)(gate * HH + c0 + l15) * HH + quad * 8;
#pragma unroll
            for (int kk = 0; kk < 16; ++kk) whEf[kk] = ldb8(Be + kk * 32);
        }
        float biE[4], wiE[4];
        if (w < 2) {
#pragma unroll
            for (int gg = 0; gg < 4; ++gg) {
                int rg = gg * HH + c0 + l15;
                biE[gg] = enc_b[rg];
                wiE[gg] = enc_Wi[rg];
            }
        }
        for (int t = 0; t < LL; ++t) {
            if (t > 0) {
                for (int e = tid; e < 1024; e += 512) {
                    int row = e >> 6, bo = (e & 63) << 4;
                    bf16x8 v = ldb8_dev(enc_out + ((size_t)(b0 + row) * LL + (t - 1)) * HH + (bo >> 1));
                    *(bf16x8*)(bufA + (row << 10) + (bo ^ ((row & 7) << 4))) = v;
                }
                __syncthreads();
                f32x4 acc = {};
#pragma unroll
                for (int kk = 0; kk < 16; ++kk)
                    acc = __builtin_amdgcn_mfma_f32_16x16x32_bf16(ldfragA(bufA, l15, quad, kk),
                                                                  whEf[kk], acc, 0, 0, 0);
#pragma unroll
                for (int r = 0; r < 4; ++r)
                    bufB[(ct * 4 + gate) * 256 + (quad * 4 + r) * 16 + l15] = acc[r];
                __syncthreads();
            }
            if (w < 2) {
#pragma unroll
                for (int r = 0; r < 4; ++r) {
                    int b = b0 + quad * 4 + r;
                    float xv = (float)xs[b * LL + t];
                    float zz[4];
#pragma unroll
                    for (int gg = 0; gg < 4; ++gg)
                        zz[gg] = (t > 0 ? bufB[(w * 4 + gg) * 256 + (quad * 4 + r) * 16 + l15] : 0.f)
                                 + biE[gg] + xv * wiE[gg];
                    float c_ = sigm(zz[1]) * creg[r] + sigm(zz[0]) * tanh_(zz[2]);
                    creg[r] = c_;
                    unsigned hv = (unsigned)f2bf(sigm(zz[3]) * tanh_(c_));
                    st_pair_dev(&enc_out[((size_t)b * LL + t) * HH + c0 + l15], hv, lane);
                    if (t == LL - 1) st_pair_dev(&hdec[(size_t)b * HH + c0 + l15], hv, lane);
                }
            }
            gsync_nf(flags, myflag, g * 16, 16, ++tgt);
        }
    }

    // ---------------- enc_w1 = enc_out @ w1^T (cached; fenced group publish) ----------------
    {
        int lw = m * 8 + w;
        for (int it = 0; it < 8; ++it) {
            int task = it * 128 + lw;
            int mt = task >> 3;
            int n0 = (task & 7) << 6;
            size_t m0 = (size_t)b0 * LL + (size_t)mt * 16;
            f32x4 acc[4] = {};
            const us* Ar = enc_out + (m0 + l15) * HH + quad * 8;
            const us* Br = w1B + (size_t)(n0 + l15) * HH + quad * 8;
#pragma unroll 8
            for (int kk = 0; kk < 16; ++kk) {
                bf16x8 a = ldb8(Ar + kk * 32);
#pragma unroll
                for (int tt = 0; tt < 4; ++tt) {
                    bf16x8 bv = ldb8(Br + (size_t)tt * 16 * HH + kk * 32);
                    acc[tt] = __builtin_amdgcn_mfma_f32_16x16x32_bf16(a, bv, acc[tt], 0, 0, 0);
                }
            }
#pragma unroll
            for (int tt = 0; tt < 4; ++tt)
#pragma unroll
                for (int r = 0; r < 4; ++r)
                    enc_w1[(m0 + quad * 4 + r) * HH + n0 + tt * 16 + l15] = f2bf(acc[tt][r]);
        }
    }
    gsync_f(flags, myflag, 0, 256, ++tgt);

    // ---------------- per-block residences: enc_out[b] -> LDS, enc_w1[b] -> registers ----------------
    {
        const i32x4* src = (const i32x4*)(const void*)(enc_out + (size_t)(b0 + m) * LL * HH);
        i32x4* dst = (i32x4*)(void*)eos;
        for (int i = tid; i < 8192; i += 512) dst[i] = src[i];
    }
    bf16x8 ew1f[16];  // thread (w,lane): rows i*8+w, cols lane*8..+7 of enc_w1[b0+m]
    {
        const us* p = enc_w1 + ((size_t)(b0 + m) * LL + w) * HH + lane * 8;
#pragma unroll
        for (int i = 0; i < 16; ++i) ew1f[i] = ldb8(p + (size_t)i * 8 * HH);
    }
    __syncthreads();

    // ---------------- decoder weight fragments into registers (once) ----------------
    bf16x8 wiRf[16], whDf[16], w2f[4];
    {
        const us* Bw = wiR + (size_t)(gate * HH + c0 + l15) * HH + quad * 8;
        const us* Bh = whD + (size_t)(gate * HH + c0 + l15) * HH + quad * 8;
#pragma unroll
        for (int kk = 0; kk < 16; ++kk) {
            wiRf[kk] = ldb8(Bw + kk * 32);
            whDf[kk] = ldb8(Bh + kk * 32);
        }
        const us* Bq = w2B + (size_t)(c0 + l15) * HH + quad * 8;  // wave covers kk = gate*4..+3
#pragma unroll
        for (int j = 0; j < 4; ++j) w2f[j] = ldb8(Bq + (gate * 4 + j) * 32);
    }
    float biD[4], wlD[4];
    if (w < 2) {
#pragma unroll
        for (int gg = 0; gg < 4; ++gg) {
            int rg = gg * HH + c0 + l15;
            biD[gg] = dec_b[rg];
            wlD[gg] = wi_last[rg];
        }
    }
    float vtk[8];  // hoisted: vt is constant across steps
#pragma unroll
    for (int j = 0; j < 8; ++j) vtk[j] = vt[lane * 8 + j];

    // ---------------- decoder: 128 steps ----------------
    for (int t = 0; t < LL; ++t) {
        const us* hcur = hdec + (size_t)(t & 1) * BB * HH;

        // ---- Q: q = h @ w2^T, K split over 8 waves, partials reduced by waves 0,1 ----
        stage_contig(hcur + (size_t)b0 * HH);    // h tile stays in bufA through Z's h-MFMA
        __syncthreads();
        {
            f32x4 acc = {};
#pragma unroll
            for (int j = 0; j < 4; ++j)
                acc = __builtin_amdgcn_mfma_f32_16x16x32_bf16(
                    ldfragA(bufA, l15, quad, gate * 4 + j), w2f[j], acc, 0, 0, 0);
#pragma unroll
            for (int r = 0; r < 4; ++r)
                bufB[(gate * 2 + ct) * 256 + (quad * 4 + r) * 16 + l15] = acc[r];
        }
        __syncthreads();
        if (w < 2) {
#pragma unroll
            for (int r = 0; r < 4; ++r) {
                float s = 0.f;
#pragma unroll
                for (int kq = 0; kq < 4; ++kq)
                    s += bufB[(kq * 2 + w) * 256 + (quad * 4 + r) * 16 + l15];
                st_pair_dev(&q[(size_t)(b0 + quad * 4 + r) * HH + c0 + l15],
                            (unsigned)f2bf(s), lane);
            }
        }
        gsync_nf(flags, myflag, g * 16, 16, ++tgt);

        // ---- A: attention for batch b0+m (q deduped via LDS; scores from REGS; ctx from LDS) ----
        {
            int b = b0 + m;
            if (tid < 64)
                *(bf16x8*)(void*)(qbuf + (tid << 3)) = ldb8_dev(q + (size_t)b * HH + (tid << 3));
            __syncthreads();
            bf16x8 qv = ldb8(qbuf + (lane << 3));
            float qk[8];
#pragma unroll
            for (int j = 0; j < 8; ++j) qk[j] = (float)qv[j];
#pragma unroll 4
            for (int i = 0; i < 16; ++i) {
                int l = i * 8 + w;
                bf16x8 e8 = ew1f[i];
                float s = 0.f;
#pragma unroll
                for (int j = 0; j < 8; ++j) s += tanh_((float)e8[j] + qk[j]) * vtk[j];
#pragma unroll
                for (int off = 1; off < 64; off <<= 1) s += __shfl_xor(s, off);
                if (lane == 0) scs[l] = s;
            }
            __syncthreads();
            bool act = tid < 128;
            float sc = act ? scs[tid] : -1e30f;
            float mx = sc;
#pragma unroll
            for (int off = 1; off < 64; off <<= 1) mx = fmaxf(mx, __shfl_xor(mx, off));
            if (act && lane == 0) redm[w] = mx;
            __syncthreads();
            float M = fmaxf(redm[0], redm[1]);
            float e = act ? __expf(sc - M) : 0.f;
            float ss = e;
#pragma unroll
            for (int off = 1; off < 64; off <<= 1) ss += __shfl_xor(ss, off);
            if (act && lane == 0) reds[w] = ss;
            __syncthreads();
            float S = reds[0] + reds[1];
            if (act) {
                __builtin_nontemporal_store(sc - M - __logf(S), &out[((size_t)b * LL + t) * LL + tid]);
                aj[tid] = e / S;
            }
            __syncthreads();
            // context from LDS: addr = l*1024 + tid*2 -> 2-way bank alias (free)
            const us* ep = eos + tid;
            float cacc = 0.f;
#pragma unroll 16
            for (int l2 = 0; l2 < LL; ++l2) cacc += aj[l2] * bf2f(ep[(size_t)l2 * HH]);
            st_pair_dev(&ctx[(size_t)b * HH + tid], (unsigned)f2bf(cacc), tid & 63);
        }
        gsync_nf(flags, myflag, g * 16, 16, ++tgt);

        // ---- Z: dint + ctx loads issued early (hidden under h-MFMA) -> ctx-MFMA -> gates ----
        {
            float dvr[4];
            if (w < 2) {
                const float* dp = dint + t * BB + b0;   // L2-cached, no recurrence dependency
#pragma unroll
                for (int r = 0; r < 4; ++r) dvr[r] = dp[quad * 4 + r];
            }
            bf16x8 cv0 = ldb8_dev(ctx + (size_t)b0 * HH + (tid << 3));
            bf16x8 cv1 = ldb8_dev(ctx + (size_t)b0 * HH + ((size_t)(tid + 512) << 3));
            f32x4 zacc = {};
            // h part (bufA still holds h from the Q phase); ctx/dint loads in flight
#pragma unroll
            for (int kk = 0; kk < 16; ++kk)
                zacc = __builtin_amdgcn_mfma_f32_16x16x32_bf16(ldfragA(bufA, l15, quad, kk),
                                                               whDf[kk], zacc, 0, 0, 0);
            __syncthreads();                      // everyone done reading h from bufA
            {
                int e = tid, row = e >> 6, bo = (e & 63) << 4;
                *(bf16x8*)(bufA + (row << 10) + (bo ^ ((row & 7) << 4))) = cv0;
                e = tid + 512; row = e >> 6; bo = (e & 63) << 4;
                *(bf16x8*)(bufA + (row << 10) + (bo ^ ((row & 7) << 4))) = cv1;
            }
            __syncthreads();
#pragma unroll
            for (int kk = 0; kk < 16; ++kk)
                zacc = __builtin_amdgcn_mfma_f32_16x16x32_bf16(ldfragA(bufA, l15, quad, kk),
                                                               wiRf[kk], zacc, 0, 0, 0);
#pragma unroll
            for (int r = 0; r < 4; ++r)
                bufB[(ct * 4 + gate) * 256 + (quad * 4 + r) * 16 + l15] = zacc[r];
            __syncthreads();
            if (w < 2) {
                us* hnxt = hdec + (size_t)((t + 1) & 1) * BB * HH;
#pragma unroll
                for (int r = 0; r < 4; ++r) {
                    int b = b0 + quad * 4 + r;
                    float zz[4];
#pragma unroll
                    for (int gg = 0; gg < 4; ++gg)
                        zz[gg] = bufB[(w * 4 + gg) * 256 + (quad * 4 + r) * 16 + l15]
                                 + biD[gg] + dvr[r] * wlD[gg];
                    float c_ = sigm(zz[1]) * creg[r] + sigm(zz[0]) * tanh_(zz[2]);
                    creg[r] = c_;
                    st_pair_dev(&hnxt[(size_t)b * HH + c0 + l15],
                                (unsigned)f2bf(sigm(zz[3]) * tanh_(c_)), lane);
                }
            }
        }
        gsync_nf(flags, myflag, g * 16, 16, ++tgt);
    }
}

extern "C" void kernel_launch(void* const* d_in, const int* in_sizes, int n_in,
                              void* d_out, int out_size, void* d_ws, size_t ws_size,
                              hipStream_t stream) {
    const int* xs = (const int*)d_in[0];
    const int* argsort = (const int*)d_in[2];
    const float* enc_Wi = (const float*)d_in[3];
    const float* enc_Wh = (const float*)d_in[4];
    const float* enc_b = (const float*)d_in[5];
    const float* dec_Wi = (const float*)d_in[6];
    const float* dec_Wh = (const float*)d_in[7];
    const float* dec_b = (const float*)d_in[8];
    const float* w1 = (const float*)d_in[9];
    const float* w2 = (const float*)d_in[10];
    const float* vt = (const float*)d_in[11];
    float* out = (float*)d_out;
    char* ws = (char*)d_ws;

    static bool attr_done = false;
    if (!attr_done) {
        hipFuncSetAttribute((const void*)k_mega, hipFuncAttributeMaxDynamicSharedMemorySize, 155648);
        attr_done = true;
    }

    hipMemsetAsync(ws, 0, 16384, stream);

    void* kargs[] = {&xs, &argsort, &enc_Wi, &enc_Wh, &enc_b, &dec_Wi, &dec_Wh, &dec_b,
                     &w1, &w2, &vt, &out, &ws};
    hipLaunchCooperativeKernel((void*)k_mega, dim3(256), dim3(512), kargs, 155648, stream);

    (void)in_sizes; (void)n_in; (void)out_size; (void)ws_size;
}